// Round 5
// baseline (2827.755 us; speedup 1.0000x reference)
//
#include <hip/hip_runtime.h>
#include <math.h>

#define NB 512
#define NN 256
#define N_ITERS 400
#define KAPPA_F 0.1f

typedef _Float16 half2_t __attribute__((ext_vector_type(2)));
typedef _Float16 half8_t __attribute__((ext_vector_type(8)));

__device__ inline float fdot2f(half2_t a, half2_t b, float c) {
#if __has_builtin(__builtin_amdgcn_fdot2)
  return __builtin_amdgcn_fdot2(a, b, c, false);
#else
  return (float)a.x * (float)b.x + (float)a.y * (float)b.y + c;
#endif
}

// R5. Evidence chain:
//  R2: pressure model validated (fit budget -> 0.5MB writes).
//  R3/R4: VGPR pinned 128, loop clean by R4 (46MB = Gram-phase one-time).
//  R4 residual: 6400 cy/iter vs ~2000 modeled. Cause = STRUCTURE: per iter,
//  wave 0 runs combine+grad+Michelot serially (~1500-2000cy) while 7 waves
//  park at a barrier, x2 barrier drains. VALUBusy 36% / Occ 24% match.
// Fix: REDUNDANT phase B. Every wave's 64 lanes x 4 row-groups cover all 256
// rows, so each wave computes combine+grad+projection itself on identical
// inputs (bitwise-identical across waves -> early-exit vote unchanged).
//  - barriers 2 -> 1 (only cross-wave data = parts, double-buffered)
//  - w fully register-resident; fp16 copy in PRIVATE per-wave LDS slot
//  - dot(w,G2w) from combined q2 -> dpart/dslot machinery deleted
//  - wave reduce = 6 DPP adds + readlane63 (uniform scalar, no ds-shuffle)
//  - mus/diag preloaded to regs (diag fold = unconditional fmaf with 0-or-d)

#define PAIR(V, K) __builtin_shufflevector(V, V, 2*(K), 2*(K)+1)

template <int CTRL, int RMASK>
__device__ inline float dpp_add(float v) {
  int s = __builtin_amdgcn_update_dpp(0, __float_as_int(v), CTRL, RMASK, 0xF, true);
  return v + __int_as_float(s);
}
// full 64-lane sum -> uniform scalar (lane63 holds total; readlane -> SGPR)
__device__ inline float wave_sum_sgpr(float v) {
  v = dpp_add<0xB1, 0xF>(v);    // quad_perm xor1
  v = dpp_add<0x4E, 0xF>(v);    // quad_perm xor2
  v = dpp_add<0x141,0xF>(v);    // row_half_mirror
  v = dpp_add<0x140,0xF>(v);    // row_mirror -> per-16-row sums, all lanes
  v = dpp_add<0x142,0xA>(v);    // row_bcast15 into rows 1,3
  v = dpp_add<0x143,0xC>(v);    // row_bcast31 into rows 2,3 -> lane63 total
  return __int_as_float(__builtin_amdgcn_readlane(__float_as_int(v), 63));
}

// ---- loose half2 G register names: P in {e0_..e3_, h0_..h3_}
#define DECLROW(P) half2_t P##0,P##1,P##2,P##3,P##4,P##5,P##6,P##7, \
                           P##8,P##9,P##10,P##11,P##12,P##13,P##14,P##15;

// ---- Gram accumulators / MACs
#define ZA(J) cA##J.x=0.f; cA##J.y=0.f; cA##J.z=0.f; cA##J.w=0.f;
#define ZB(J) cB##J.x=0.f; cB##J.y=0.f; cB##J.z=0.f; cB##J.w=0.f;
#define ZALL() ZA(0) ZA(1) ZA(2) ZA(3) ZA(4) ZA(5) ZA(6) ZA(7) \
               ZB(0) ZB(1) ZB(2) ZB(3) ZB(4) ZB(5) ZB(6) ZB(7)
#define GMA(J,F) { cA##J.x=fmaf(a0,F.x,cA##J.x); cA##J.y=fmaf(a0,F.y,cA##J.y); \
                   cA##J.z=fmaf(a0,F.z,cA##J.z); cA##J.w=fmaf(a0,F.w,cA##J.w); }
#define GMB(J,F) { cB##J.x=fmaf(a1,F.x,cB##J.x); cB##J.y=fmaf(a1,F.y,cB##J.y); \
                   cB##J.z=fmaf(a1,F.z,cB##J.z); cB##J.w=fmaf(a1,F.w,cB##J.w); }

// Two-row-group Gram pass (rows RB+lane, RB+64+lane) — A-Gram
#define GRAM2(SRC, RB, DOFRO) do { \
  const float4* __restrict__ src4 = (const float4*)(SRC); \
  ZALL() \
  float4 st0 = src4[t], st1 = src4[512 + t]; \
  _Pragma("unroll 1") \
  for (int kt = 0; kt < 16; ++kt) { \
    __syncthreads(); \
    ((float4*)As)[t] = st0; \
    ((float4*)As)[512 + t] = st1; \
    if (DOFRO) { fro += st0.x*st0.x + st0.y*st0.y + st0.z*st0.z + st0.w*st0.w; \
                 fro += st1.x*st1.x + st1.y*st1.y + st1.z*st1.z + st1.w*st1.w; } \
    __syncthreads(); \
    if (kt < 15) { st0 = src4[(kt+1)*1024 + t]; st1 = src4[(kt+1)*1024 + 512 + t]; } \
    _Pragma("unroll 1") \
    for (int k = 0; k < 16; ++k) { \
      const float* rowp = As + k * NN; \
      float a0 = rowp[(RB) + lane]; \
      float a1 = rowp[(RB) + 64 + lane]; \
      const float4* rp4 = (const float4*)(rowp + 32 * wv); \
      { float4 f0=rp4[0], f1=rp4[1], f2=rp4[2], f3=rp4[3]; \
        GMA(0,f0) GMA(1,f1) GMA(2,f2) GMA(3,f3) \
        GMB(0,f0) GMB(1,f1) GMB(2,f2) GMB(3,f3) } \
      { float4 f4=rp4[4], f5=rp4[5], f6=rp4[6], f7=rp4[7]; \
        GMA(4,f4) GMA(5,f5) GMA(6,f6) GMA(7,f7) \
        GMB(4,f4) GMB(5,f5) GMB(6,f6) GMB(7,f7) } \
    } \
  } \
} while (0)

// Single-row-group Gram pass (row RB+lane) — U-Gram (caps peak pressure)
#define GRAM1(SRC, RB, DOFRO) do { \
  const float4* __restrict__ src4 = (const float4*)(SRC); \
  ZA(0) ZA(1) ZA(2) ZA(3) ZA(4) ZA(5) ZA(6) ZA(7) \
  float4 st = src4[t]; \
  _Pragma("unroll 1") \
  for (int kt = 0; kt < 32; ++kt) { \
    __syncthreads(); \
    ((float4*)As)[t] = st; \
    if (DOFRO) fro += st.x*st.x + st.y*st.y + st.z*st.z + st.w*st.w; \
    __syncthreads(); \
    if (kt < 31) st = src4[(kt + 1) * 512 + t]; \
    _Pragma("unroll 1") \
    for (int k = 0; k < 8; ++k) { \
      const float* rowp = As + k * NN; \
      float a0 = rowp[(RB) + lane]; \
      const float4* rp4 = (const float4*)(rowp + 32 * wv); \
      { float4 f0=rp4[0], f1=rp4[1], f2=rp4[2], f3=rp4[3]; \
        GMA(0,f0) GMA(1,f1) GMA(2,f2) GMA(3,f3) } \
      { float4 f4=rp4[4], f5=rp4[5], f6=rp4[6], f7=rp4[7]; \
        GMA(4,f4) GMA(5,f5) GMA(6,f6) GMA(7,f7) } \
    } \
  } \
} while (0)

// Pack one float4 (4 cols) -> 2 loose half2; diag -> fp32 LDS, zeroed in fp16
#define PACK4(PA, PB, C, J4, DIAG) { \
  float x0=C.x, x1=C.y, x2=C.z, x3=C.w; \
  const int cb = 32*wv + 4*(J4); \
  if (cb+0==row_) { DIAG[row_]=x0; x0=0.f; } \
  if (cb+1==row_) { DIAG[row_]=x1; x1=0.f; } \
  if (cb+2==row_) { DIAG[row_]=x2; x2=0.f; } \
  if (cb+3==row_) { DIAG[row_]=x3; x3=0.f; } \
  PA.x=(_Float16)x0; PA.y=(_Float16)x1; \
  PB.x=(_Float16)x2; PB.y=(_Float16)x3; }

#define PACKROW(P, CP, DIAG) { \
  PACK4(P##0,  P##1,  c##CP##0, 0, DIAG) \
  PACK4(P##2,  P##3,  c##CP##1, 1, DIAG) \
  PACK4(P##4,  P##5,  c##CP##2, 2, DIAG) \
  PACK4(P##6,  P##7,  c##CP##3, 3, DIAG) \
  PACK4(P##8,  P##9,  c##CP##4, 4, DIAG) \
  PACK4(P##10, P##11, c##CP##5, 5, DIAG) \
  PACK4(P##12, P##13, c##CP##6, 6, DIAG) \
  PACK4(P##14, P##15, c##CP##7, 7, DIAG) }

// 16 fdot2 for one row (cols ascending; same accumulation order as R4)
#define DOTROW(ACC, P) \
  ACC = fdot2f(P##0,  PAIR(uh0,0), ACC); \
  ACC = fdot2f(P##1,  PAIR(uh0,1), ACC); \
  ACC = fdot2f(P##2,  PAIR(uh0,2), ACC); \
  ACC = fdot2f(P##3,  PAIR(uh0,3), ACC); \
  ACC = fdot2f(P##4,  PAIR(uh1,0), ACC); \
  ACC = fdot2f(P##5,  PAIR(uh1,1), ACC); \
  ACC = fdot2f(P##6,  PAIR(uh1,2), ACC); \
  ACC = fdot2f(P##7,  PAIR(uh1,3), ACC); \
  ACC = fdot2f(P##8,  PAIR(uh2,0), ACC); \
  ACC = fdot2f(P##9,  PAIR(uh2,1), ACC); \
  ACC = fdot2f(P##10, PAIR(uh2,2), ACC); \
  ACC = fdot2f(P##11, PAIR(uh2,3), ACC); \
  ACC = fdot2f(P##12, PAIR(uh3,0), ACC); \
  ACC = fdot2f(P##13, PAIR(uh3,1), ACC); \
  ACC = fdot2f(P##14, PAIR(uh3,2), ACC); \
  ACC = fdot2f(P##15, PAIR(uh3,3), ACC);

// 8-way partial combine from PP (same order as R4)
#define COMB(PP, I) { \
  const int rr = 64 * (I) + lane; \
  float2 x0 = PP[rr],          x1 = PP[NN + rr]; \
  float2 x2 = PP[2*NN + rr],   x3 = PP[3*NN + rr]; \
  float2 x4 = PP[4*NN + rr],   x5 = PP[5*NN + rr]; \
  float2 x6 = PP[6*NN + rr],   x7 = PP[7*NN + rr]; \
  q1##I = ((x0.x+x1.x)+(x2.x+x3.x))+((x4.x+x5.x)+(x6.x+x7.x)); \
  q2##I = ((x0.y+x1.y)+(x2.y+x3.y))+((x4.y+x5.y)+(x6.y+x7.y)); }

__global__
__attribute__((amdgpu_flat_work_group_size(512, 512)))
__attribute__((amdgpu_waves_per_eu(1, 2)))
void mvo_kernel(const float* __restrict__ mu,
                const float* __restrict__ U,
                const float* __restrict__ A,
                float* __restrict__ out)
{
  __shared__ alignas(16) float2 partsbuf[2][8 * NN];  // 32 KB; buf0 = Gram staging
  __shared__ alignas(16) _Float16 whsl[8 * NN];       // 4 KB private w-fp16 slots
  __shared__ float mus[NN];
  __shared__ float diag1[NN];                         // fp32 diag of U^T U
  __shared__ float diag2[NN];                         // fp32 diag of A^T A
  __shared__ float slotA[8];
  __shared__ float slotB[8];

  float* As = (float*)&partsbuf[0][0];                // 16 KB staging

  const int t    = threadIdx.x;
  const int b    = blockIdx.x;
  const int lane = t & 63;
  const int wv   = t >> 6;          // col-chunk 0..7 (32 cols each)

  const float* __restrict__ Ub = U + (size_t)b * NN * NN;
  const float* __restrict__ Ab = A + (size_t)b * NN * NN;

  if (t < NN) mus[t] = mu[b * NN + t];

  DECLROW(e0_) DECLROW(e1_) DECLROW(e2_) DECLROW(e3_)
  DECLROW(h0_) DECLROW(h1_) DECLROW(h2_) DECLROW(h3_)
  float4 cA0,cA1,cA2,cA3,cA4,cA5,cA6,cA7;
  float4 cB0,cB1,cB2,cB3,cB4,cB5,cB6,cB7;
  float fro, d1, d2;

  // ---- Gram: A^T A (2-group passes), then U^T U (1-group x4) ----
  fro = 0.f;
  GRAM2(Ab, 0, 1);
  { const int row_ = lane;        PACKROW(h0_, A, diag2) }
  { const int row_ = 64 + lane;   PACKROW(h1_, B, diag2) }
  GRAM2(Ab, 128, 0);
  { const int row_ = 128 + lane;  PACKROW(h2_, A, diag2) }
  { const int row_ = 192 + lane;  PACKROW(h3_, B, diag2) }
  d2 = fro;
  fro = 0.f;
  GRAM1(Ub, 0, 1);
  { const int row_ = lane;        PACKROW(e0_, A, diag1) }
  GRAM1(Ub, 64, 0);
  { const int row_ = 64 + lane;   PACKROW(e1_, A, diag1) }
  GRAM1(Ub, 128, 0);
  { const int row_ = 128 + lane;  PACKROW(e2_, A, diag1) }
  GRAM1(Ub, 192, 0);
  { const int row_ = 192 + lane;  PACKROW(e3_, A, diag1) }
  d1 = fro;

  // step on the legacy shfl path (bitwise-stable vs R2-R4)
  #pragma unroll
  for (int m = 1; m < 64; m <<= 1) {
    d1 += __shfl_xor(d1, m, 64);
    d2 += __shfl_xor(d2, m, 64);
  }
  if (lane == 0) { slotA[wv] = d1; slotB[wv] = d2; }
  __syncthreads();
  float froU2 = 0.f, froA2 = 0.f;
  #pragma unroll
  for (int k = 0; k < 8; ++k) { froU2 += slotA[k]; froA2 += slotB[k]; }
  const float step = 1.0f / (froU2 + KAPPA_F * sqrtf(froA2) + 1.0f);

  // ---- loop-invariant preloads (regs) ----
  const int dsel = lane >> 5;
  const float mu_r0 = mus[lane],       mu_r1 = mus[64 + lane];
  const float mu_r2 = mus[128 + lane], mu_r3 = mus[192 + lane];
  const float fdU0 = (wv == dsel)     ? diag1[lane]       : 0.f;
  const float fdA0 = (wv == dsel)     ? diag2[lane]       : 0.f;
  const float fdU1 = (wv == 2 + dsel) ? diag1[64 + lane]  : 0.f;
  const float fdA1 = (wv == 2 + dsel) ? diag2[64 + lane]  : 0.f;
  const float fdU2 = (wv == 4 + dsel) ? diag1[128 + lane] : 0.f;
  const float fdA2 = (wv == 4 + dsel) ? diag2[128 + lane] : 0.f;
  const float fdU3 = (wv == 6 + dsel) ? diag1[192 + lane] : 0.f;
  const float fdA3 = (wv == 6 + dsel) ? diag2[192 + lane] : 0.f;

  // w fully in registers; fp16 col-window in uh regs (init = splat 1/256)
  float w_r0 = 1.0f/256.0f, w_r1 = 1.0f/256.0f, w_r2 = 1.0f/256.0f, w_r3 = 1.0f/256.0f;
  half8_t uh0;
  { const _Float16 hv = (_Float16)(1.0f/256.0f);
    uh0[0]=hv; uh0[1]=hv; uh0[2]=hv; uh0[3]=hv;
    uh0[4]=hv; uh0[5]=hv; uh0[6]=hv; uh0[7]=hv; }
  half8_t uh1 = uh0, uh2 = uh0, uh3 = uh0;

  _Float16* myslot = whsl + (wv << 8);                 // private per-wave slot
  const half8_t* myslot8 = (const half8_t*)myslot;
  float tau_ws = -1e30f;                               // warm-start tau (reg)
  int pb = 0;

  // ---------------- PGD iterations: ONE barrier per iter ------------------
  #pragma unroll 1
  for (int it = 0; it < N_ITERS; ++it) {
    // Phase A: pure-register matvecs
    float p10=0.f, p11=0.f, p12=0.f, p13=0.f;
    float p20=0.f, p21=0.f, p22=0.f, p23=0.f;
    DOTROW(p10, e0_) DOTROW(p11, e1_) DOTROW(p12, e2_) DOTROW(p13, e3_)
    DOTROW(p20, h0_) DOTROW(p21, h1_) DOTROW(p22, h2_) DOTROW(p23, h3_)
    // exact fp32 diag fold (fd* is 0 on non-owning threads: +0 exactly)
    p10 = fmaf(fdU0, w_r0, p10);  p20 = fmaf(fdA0, w_r0, p20);
    p11 = fmaf(fdU1, w_r1, p11);  p21 = fmaf(fdA1, w_r1, p21);
    p12 = fmaf(fdU2, w_r2, p12);  p22 = fmaf(fdA2, w_r2, p22);
    p13 = fmaf(fdU3, w_r3, p13);  p23 = fmaf(fdA3, w_r3, p23);

    float2* P = &partsbuf[pb][0];
    P[wv * NN + lane]       = make_float2(p10, p20);
    P[wv * NN + 64 + lane]  = make_float2(p11, p21);
    P[wv * NN + 128 + lane] = make_float2(p12, p22);
    P[wv * NN + 192 + lane] = make_float2(p13, p23);
    __syncthreads();

    // Phase B: REDUNDANT on all 8 waves (identical inputs -> identical bits)
    float q10, q11, q12, q13, q20, q21, q22, q23;
    COMB(P, 0) COMB(P, 1) COMB(P, 2) COMB(P, 3)
    float dot = wave_sum_sgpr(
        fmaf(q20, w_r0, fmaf(q21, w_r1, fmaf(q22, w_r2, q23 * w_r3))));
    float nrm = sqrtf(fmaxf(dot, 1e-12f));
    float kon = KAPPA_F / nrm;
    float v0 = w_r0 - step * (q10 + kon * q20 - mu_r0);
    float v1 = w_r1 - step * (q11 + kon * q21 - mu_r1);
    float v2 = w_r2 - step * (q12 + kon * q22 - mu_r2);
    float v3 = w_r3 - step * (q13 + kon * q23 - mu_r3);

    // Warm-started Michelot (break on stable count is exact; Newton on a
    // convex piecewise-linear eq -> finite, typically 2-3 rounds)
    float tau = tau_ws;
    float cprev = -1.f;
    #pragma unroll 1
    for (int ms = 0; ms < 24; ++ms) {
      float s2 = (v0 > tau ? v0 : 0.f) + (v1 > tau ? v1 : 0.f)
               + (v2 > tau ? v2 : 0.f) + (v3 > tau ? v3 : 0.f);
      float c2 = (v0 > tau ? 1.f : 0.f) + (v1 > tau ? 1.f : 0.f)
               + (v2 > tau ? 1.f : 0.f) + (v3 > tau ? 1.f : 0.f);
      s2 = wave_sum_sgpr(s2);
      c2 = wave_sum_sgpr(c2);
      if (c2 == cprev) break;
      tau = (s2 - 1.0f) / c2;
      cprev = c2;
    }
    float nw0 = fmaxf(v0 - tau, 0.f);
    float nw1 = fmaxf(v1 - tau, 0.f);
    float nw2 = fmaxf(v2 - tau, 0.f);
    float nw3 = fmaxf(v3 - tau, 0.f);
    int conv = __all((nw0 == w_r0) && (nw1 == w_r1) &&
                     (nw2 == w_r2) && (nw3 == w_r3));
    w_r0 = nw0; w_r1 = nw1; w_r2 = nw2; w_r3 = nw3;
    tau_ws = tau;

    // refresh private fp16 copy + reload my col-window (no barrier needed)
    myslot[lane]        = (_Float16)nw0;
    myslot[64 + lane]   = (_Float16)nw1;
    myslot[128 + lane]  = (_Float16)nw2;
    myslot[192 + lane]  = (_Float16)nw3;
    uh0 = myslot8[4 * wv + 0];
    uh1 = myslot8[4 * wv + 1];
    uh2 = myslot8[4 * wv + 2];
    uh3 = myslot8[4 * wv + 3];

    pb ^= 1;
    if (conv) break;   // uniform across waves (bitwise-identical B)
  }

  // Final renormalize + store (all waves hold identical w; wave 0 stores)
  if (wv == 0) {
    float s = wave_sum_sgpr(w_r0 + w_r1 + w_r2 + w_r3);
    float inv = 1.0f / (s + 1e-12f);
    float* ob = out + b * NN;
    ob[lane]        = w_r0 * inv;
    ob[64 + lane]   = w_r1 * inv;
    ob[128 + lane]  = w_r2 * inv;
    ob[192 + lane]  = w_r3 * inv;
  }
}

extern "C" void kernel_launch(void* const* d_in, const int* in_sizes, int n_in,
                              void* d_out, int out_size, void* d_ws, size_t ws_size,
                              hipStream_t stream) {
  const float* mu = (const float*)d_in[0];
  const float* U  = (const float*)d_in[1];
  const float* A  = (const float*)d_in[2];
  float* out = (float*)d_out;
  hipLaunchKernelGGL(mvo_kernel, dim3(NB), dim3(512), 0, stream, mu, U, A, out);
}